// Round 3
// baseline (898.078 us; speedup 1.0000x reference)
//
#include <hip/hip_runtime.h>
#include <stdint.h>

#define MM 8192
#define NN 4096
#define KK 4096

typedef __attribute__((ext_vector_type(8))) short short8;
typedef __attribute__((ext_vector_type(4))) float floatx4;
typedef int int4a __attribute__((ext_vector_type(4), aligned(4)));  // 4B-aligned 16B load

// fp32 -> bf16 round-to-nearest-even
__device__ inline unsigned short f2bf(float f) {
    unsigned int u = __float_as_uint(f);
    u += 0x7FFFu + ((u >> 16) & 1u);
    return (unsigned short)(u >> 16);
}

// Convert x [8192,4096] fp32 -> bf16, 8 elems/thread, coalesced.
__global__ void prep_x_kernel(const float* __restrict__ x, unsigned short* __restrict__ xb) {
    size_t i = (size_t)blockIdx.x * 256 + threadIdx.x;   // octet index, MM*KK/8 total
    const float4* x4 = (const float4*)x;
    float4 v0 = x4[i * 2];
    float4 v1 = x4[i * 2 + 1];
    ushort4 o0, o1;
    o0.x = f2bf(v0.x); o0.y = f2bf(v0.y); o0.z = f2bf(v0.z); o0.w = f2bf(v0.w);
    o1.x = f2bf(v1.x); o1.y = f2bf(v1.y); o1.z = f2bf(v1.z); o1.w = f2bf(v1.w);
    *(ushort4*)(xb + i * 8)     = o0;
    *(ushort4*)(xb + i * 8 + 4) = o1;
}

// vals (8191 fp32) -> two bf16 copies: vlo[i]=vals[i], vhi[i]=vals[i+1].
__global__ void prep_vals_kernel(const float* __restrict__ vals,
                                 unsigned short* __restrict__ vlo,
                                 unsigned short* __restrict__ vhi) {
    int i = blockIdx.x * 256 + threadIdx.x;
    if (i < KK + NN - 1) {
        unsigned short s = f2bf(vals[i]);
        vlo[i] = s;
        if (i > 0) vhi[i - 1] = s;
    }
}

// C[m,n] = sum_k A[m,k] * W[n,k],  W[n,k] = vals[4095 - n + k] (Toeplitz).
// Zero LDS, zero barriers: A fragments streamed straight from global
// (L1/L2-cached; 2 waves per block share rows), B fragments from the
// 16 KB L1-resident bf16 vals copies. One-half-K-step register prefetch
// so the compiler emits fine-grained vmcnt(N) pipelining (AITER-style).
__global__ __launch_bounds__(256, 3) void gemm_kernel(
        const unsigned short* __restrict__ A,
        const unsigned short* __restrict__ vlo,
        const unsigned short* __restrict__ vhi,
        float* __restrict__ C) {
    const int tid  = threadIdx.x;
    const int lane = tid & 63;
    const int w    = tid >> 6;
    const int n0 = blockIdx.x * 128;
    const int m0 = blockIdx.y * 128;

    const int quad = lane >> 4;   // 0..3: MFMA k-group (k = quad*8 .. +7)
    const int l16  = lane & 15;
    const int wm   = (w >> 1) * 64;
    const int wn   = (w & 1) * 64;

    // A fragment pointers: af[i] = A[m0+wm+i*16+l16][k + quad*8 .. +8)
    // Lanes of one quad read 16 rows x 16B; the 4 quads cover 64B/row -> full lines.
    const unsigned short* aptr[4];
#pragma unroll
    for (int i = 0; i < 4; ++i)
        aptr[i] = A + (size_t)(m0 + wm + i * 16 + l16) * KK + quad * 8;

    // B fragment pointers: idx = 4095 - n_eff + quad*8, n_eff = n0+wn+l16+j*16.
    // Parity is k-invariant -> lo/hi copy select hoists out of the loop.
    const unsigned short* bptr[4];
#pragma unroll
    for (int j = 0; j < 4; ++j) {
        int idx0 = (NN - 1) - (n0 + wn + l16) - j * 16 + quad * 8;
        bptr[j] = (idx0 & 1) ? (vhi + (idx0 - 1)) : (vlo + idx0);
    }

    floatx4 acc[4][4] = {};
    short8 a0[4], b0[4], a1[4], b1[4];

#define LOADK(af, bf, k)                                               \
    do {                                                               \
        _Pragma("unroll")                                              \
        for (int i = 0; i < 4; ++i)                                    \
            (af)[i] = *(const short8*)(aptr[i] + (k));                 \
        _Pragma("unroll")                                              \
        for (int j = 0; j < 4; ++j) {                                  \
            int4a t = *(const int4a*)(bptr[j] + (k));                  \
            __builtin_memcpy(&(bf)[j], &t, 16);                        \
        }                                                              \
    } while (0)

#define MFMA16(af, bf)                                                 \
    do {                                                               \
        _Pragma("unroll")                                              \
        for (int i = 0; i < 4; ++i)                                    \
            _Pragma("unroll")                                          \
            for (int j = 0; j < 4; ++j)                                \
                acc[i][j] = __builtin_amdgcn_mfma_f32_16x16x32_bf16(   \
                    (af)[i], (bf)[j], acc[i][j], 0, 0, 0);             \
    } while (0)

    LOADK(a0, b0, 0);
    for (int k = 0; k < KK; k += 64) {
        LOADK(a1, b1, k + 32);
        MFMA16(a0, b0);
        LOADK(a0, b0, k + 64);   // final iter prefetches k=KK: lands in ws slack, unused
        MFMA16(a1, b1);
    }

    // Epilogue: C/D layout col = lane&15, row = quad*4 + reg (m89-verified)
    float* cW = C + (size_t)(m0 + wm) * NN + (n0 + wn);
#pragma unroll
    for (int i = 0; i < 4; ++i) {
#pragma unroll
        for (int j = 0; j < 4; ++j) {
            float* cp = cW + (size_t)(i * 16 + quad * 4) * NN + j * 16 + l16;
#pragma unroll
            for (int r = 0; r < 4; ++r)
                cp[(size_t)r * NN] = acc[i][j][r];
        }
    }
#undef LOADK
#undef MFMA16
}

extern "C" void kernel_launch(void* const* d_in, const int* in_sizes, int n_in,
                              void* d_out, int out_size, void* d_ws, size_t ws_size,
                              hipStream_t stream) {
    const float* x    = (const float*)d_in[0];
    const float* vals = (const float*)d_in[1];
    float* out = (float*)d_out;

    // ws layout: xb (67.1 MB) | 64 KB slack for A over-prefetch | vlo(32 KB) | vhi(32 KB)
    unsigned short* xb  = (unsigned short*)d_ws;
    unsigned short* vlo = xb + (size_t)MM * KK + 32768;
    unsigned short* vhi = vlo + 16384;

    prep_x_kernel<<<MM * KK / 8 / 256, 256, 0, stream>>>(x, xb);
    prep_vals_kernel<<<(KK + NN - 1 + 255) / 256, 256, 0, stream>>>(vals, vlo, vhi);

    dim3 grid(NN / 128, MM / 128);
    gemm_kernel<<<grid, 256, 0, stream>>>(xb, vlo, vhi, out);
}

// Round 4
// 522.739 us; speedup vs baseline: 1.7180x; 1.7180x over previous
//
#include <hip/hip_runtime.h>
#include <stdint.h>

#define MM 8192
#define NN 4096
#define KK 4096

typedef __attribute__((ext_vector_type(8))) short short8;
typedef __attribute__((ext_vector_type(4))) float floatx4;
typedef int int4a __attribute__((ext_vector_type(4), aligned(4)));  // 4B-aligned 16B load

// fp32 -> bf16 round-to-nearest-even
__device__ inline unsigned short f2bf(float f) {
    unsigned int u = __float_as_uint(f);
    u += 0x7FFFu + ((u >> 16) & 1u);
    return (unsigned short)(u >> 16);
}

// Convert x [8192,4096] fp32 -> bf16, 8 elems/thread, coalesced.
__global__ void prep_x_kernel(const float* __restrict__ x, unsigned short* __restrict__ xb) {
    size_t i = (size_t)blockIdx.x * 256 + threadIdx.x;
    const float4* x4 = (const float4*)x;
    float4 v0 = x4[i * 2];
    float4 v1 = x4[i * 2 + 1];
    ushort4 o0, o1;
    o0.x = f2bf(v0.x); o0.y = f2bf(v0.y); o0.z = f2bf(v0.z); o0.w = f2bf(v0.w);
    o1.x = f2bf(v1.x); o1.y = f2bf(v1.y); o1.z = f2bf(v1.z); o1.w = f2bf(v1.w);
    *(ushort4*)(xb + i * 8)     = o0;
    *(ushort4*)(xb + i * 8 + 4) = o1;
}

// vals (8191 fp32) -> two bf16 copies: vlo[i]=vals[i], vhi[i]=vals[i+1].
// Dual copy makes any even element offset 4-byte aligned in one of the two.
__global__ void prep_vals_kernel(const float* __restrict__ vals,
                                 unsigned short* __restrict__ vlo,
                                 unsigned short* __restrict__ vhi) {
    int i = blockIdx.x * 256 + threadIdx.x;
    if (i < KK + NN - 1) {
        unsigned short s = f2bf(vals[i]);
        vlo[i] = s;
        if (i > 0) vhi[i - 1] = s;
    }
}

#define GLOAD_LDS16(g, l)                                              \
    __builtin_amdgcn_global_load_lds(                                  \
        (__attribute__((address_space(1))) void*)(g),                  \
        (__attribute__((address_space(3))) void*)(l), 16, 0, 0)

// C[m,n] = sum_k A[m,k] * W[n,k],  W[n,k] = vals[4095 - n + k] (Toeplitz).
// A staged in LDS, DOUBLE-BUFFERED (2 x 128x64 tiles, XOR-8 swizzle -> 0 bank
// conflicts, measured R2). One barrier per K=64 step; the 4 global_load_lds
// for tile t+1 issue immediately AFTER the barrier, so their latency is
// covered by tile t's compute before the next barrier's vmcnt(0) drain.
// B fragments come straight from the 16KB L1-resident bf16 vals copies.
__global__ __launch_bounds__(256) void gemm_kernel(
        const unsigned short* __restrict__ A,
        const unsigned short* __restrict__ vlo,
        const unsigned short* __restrict__ vhi,
        float* __restrict__ C) {
    __shared__ unsigned short ldsA[2][128 * 64];   // 2 x 16 KB

    const int tid  = threadIdx.x;
    const int lane = tid & 63;
    const int w    = tid >> 6;
    const int n0 = blockIdx.x * 128;
    const int m0 = blockIdx.y * 128;

    const int quad = lane >> 4;   // 0..3 (MFMA k-group)
    const int l16  = lane & 15;
    const int wm   = (w >> 1) * 64;
    const int wn   = (w & 1) * 64;

    // ---- A staging: wave w stages rows [w*32, w*32+32), 4 GLL of 8 rows each.
    // Lane l -> row (l>>3), slot (l&7); slot s of row r holds chunk s^(r&7).
    const int lr8 = lane >> 3;
    const int cg  = (lane & 7) ^ (lr8 & 7);
    const unsigned short* aSrc = A + (size_t)(m0 + w * 32 + lr8) * KK + cg * 8;
    unsigned short* aDst0 = &ldsA[0][(w * 32) * 64];
    unsigned short* aDst1 = &ldsA[1][(w * 32) * 64];

#define STAGE(dst, k0)                                                 \
    do {                                                               \
        _Pragma("unroll")                                              \
        for (int g = 0; g < 4; ++g)                                    \
            GLOAD_LDS16(aSrc + (size_t)g * 8 * KK + (k0), (dst) + g * 8 * 64); \
    } while (0)

    // ---- B pointers: idx = 4095 - (n0+wn+l16+j*16) + quad*8 (+k).
    const unsigned short* bptr[4];
#pragma unroll
    for (int j = 0; j < 4; ++j) {
        int idx0 = (NN - 1) - (n0 + wn + l16) - j * 16 + quad * 8;
        bptr[j] = (idx0 & 1) ? (vhi + (idx0 - 1)) : (vlo + idx0);
    }

    floatx4 acc[4][4] = {};

    STAGE(aDst0, 0);   // prologue: tile 0 -> buf 0

    for (int k0 = 0; k0 < KK; k0 += 64) {
        const unsigned short* buf = ldsA[(k0 >> 6) & 1];
        unsigned short* nbuf = ((k0 >> 6) & 1) ? aDst0 : aDst1;

        __syncthreads();                 // tile k0 ready; buf t+1 free of readers
        if (k0 + 64 < KK) STAGE(nbuf, k0 + 64);   // prefetch overlaps compute

#pragma unroll
        for (int kh = 0; kh < 2; ++kh) {
            short8 af[4], bfr[4];
#pragma unroll
            for (int i = 0; i < 4; ++i)
                af[i] = *(const short8*)&buf[(wm + i * 16 + l16) * 64 +
                                             (((kh * 4 + quad) ^ (l16 & 7)) * 8)];
#pragma unroll
            for (int j = 0; j < 4; ++j) {
                int4a t = *(const int4a*)(bptr[j] + k0 + kh * 32);
                __builtin_memcpy(&bfr[j], &t, 16);
            }
#pragma unroll
            for (int i = 0; i < 4; ++i)
#pragma unroll
                for (int j = 0; j < 4; ++j)
                    acc[i][j] = __builtin_amdgcn_mfma_f32_16x16x32_bf16(
                        af[i], bfr[j], acc[i][j], 0, 0, 0);
        }
    }

    // Epilogue: C/D layout col = lane&15, row = quad*4 + reg (m89-verified)
    float* cW = C + (size_t)(m0 + wm) * NN + (n0 + wn);
#pragma unroll
    for (int i = 0; i < 4; ++i) {
#pragma unroll
        for (int j = 0; j < 4; ++j) {
            float* cp = cW + (size_t)(i * 16 + quad * 4) * NN + j * 16 + l16;
#pragma unroll
            for (int r = 0; r < 4; ++r)
                cp[(size_t)r * NN] = acc[i][j][r];
        }
    }
#undef STAGE
}

extern "C" void kernel_launch(void* const* d_in, const int* in_sizes, int n_in,
                              void* d_out, int out_size, void* d_ws, size_t ws_size,
                              hipStream_t stream) {
    const float* x    = (const float*)d_in[0];
    const float* vals = (const float*)d_in[1];
    float* out = (float*)d_out;

    unsigned short* xb  = (unsigned short*)d_ws;          // 67.1 MB
    unsigned short* vlo = xb + (size_t)MM * KK;
    unsigned short* vhi = vlo + 16384;

    prep_x_kernel<<<MM * KK / 8 / 256, 256, 0, stream>>>(x, xb);
    prep_vals_kernel<<<(KK + NN - 1 + 255) / 256, 256, 0, stream>>>(vals, vlo, vhi);

    dim3 grid(NN / 128, MM / 128);
    gemm_kernel<<<grid, 256, 0, stream>>>(xb, vlo, vhi, out);
}